// Round 2
// baseline (74.120 us; speedup 1.0000x reference)
//
#include <hip/hip_runtime.h>
#include <math.h>

// Problem constants (from setup_inputs: B=8, P=512, Q=4096, H=W=512)
#define BB   8
#define PP   512
#define QQ   4096
#define NPTS (BB * PP)
#define RAD2 2025.0f            // 45^2 ; |d|<=45 <=> d*d<=2025 (d is exact int)
#define INV2S2 (1.0f / 450.0f)  // 1/(2*15^2)

#define PT_BLOCKS (BB * 8)      // 64 point blocks: (b, g) = (bi>>3, bi&7)
#define CE_BLOCKS (BB * 2)      // 16 ce blocks:    (b, half) = (j>>1, j&1)
#define NBLK (PT_BLOCKS + CE_BLOCKS)   // 80

// ws layout (floats): [0..31]  CE partials (16 blocks x {num, den})
//                     [64..127] point-loss partials (64 blocks)
// Every slot the finisher reads is written unconditionally each call
// -> poison-safe, no init kernel.

// Completion counter lives in MODULE memory (never poisoned by the harness).
// Monotonic: each launch adds exactly NBLK; the block whose atomicAdd returns
// old % NBLK == NBLK-1 is the 80th completer of THIS launch -> finalizes.
// No spinning => no deadlock, no dispatch-order assumption. 64-bit => no
// wraparound phase shift.
__device__ unsigned long long g_done = 0ull;

// block-wide sum reduction (blockDim.x multiple of 64, <=512); valid at tid 0.
__device__ inline float block_reduce(float v, float* sbuf) {
#pragma unroll
    for (int off = 32; off > 0; off >>= 1) v += __shfl_down(v, off);
    const int lane = threadIdx.x & 63;
    const int wid  = threadIdx.x >> 6;
    __syncthreads();
    if (lane == 0) sbuf[wid] = v;
    __syncthreads();
    float r = (threadIdx.x < (blockDim.x >> 6)) ? sbuf[threadIdx.x] : 0.0f;
    if (wid == 0) {
#pragma unroll
        for (int off = 32; off > 0; off >>= 1) r += __shfl_down(r, off);
    }
    return r;
}

// ---------------------------------------------------------------------------
// Single fused kernel: blocks [0,64) point loss, blocks [64,80) CE, and the
// last-finishing block does the final scalar reduction (removes the k_final
// launch + its graph-node gap).
__global__ __launch_bounds__(512) void k_fused(
        const float* __restrict__ tpts, const float* __restrict__ spts,
        const float2* __restrict__ logits, const int* __restrict__ src_idx,
        const int* __restrict__ ihp, const int* __restrict__ iwp,
        float* __restrict__ part, float* __restrict__ out) {
    __shared__ unsigned int s_last;
    const int bi = blockIdx.x;
    const int t = threadIdx.x;

    if (bi < PT_BLOCKS) {
        // ---------------- point loss ----------------
        // Wave c handles point-chunk c (64 points, wave-uniform m -> LDS
        // broadcast) for 64 queries (qi = lane). Partial mins combined via
        // LDS; chunk-0 wave finishes (its wx/wy are right for query qi = t).
        __shared__ float spx[PP], spy[PP];
        __shared__ float pm[4][PP];              // [corner][c*64 + qi]
        const int b = bi >> 3, g = bi & 7;
        const float fH = (float)ihp[0];
        const float fW = (float)iwp[0];

        // stage rounded/clipped target pixel coords (512 threads <-> 512 pts)
        {
            float2 tp = ((const float2*)tpts)[b * PP + t];   // vectorized 8B
            float fx = rintf(tp.x / fH * fW);    // round-half-even = jnp.round
            float fy = rintf(tp.y / fW * fH);
            spx[t] = fminf(fmaxf(fx, 0.0f), fW - 1.0f);
            spy[t] = fminf(fmaxf(fy, 0.0f), fH - 1.0f);
        }
        __syncthreads();

        const int qi = t & 63, c = t >> 6;
        const int n = b * PP + g * 64 + qi;
        float2 sp = ((const float2*)spts)[n];                // vectorized 8B
        float sx = fminf(fmaxf(sp.x * fW, 0.0f), fW - 1.0f);
        float sy = fminf(fmaxf(sp.y * fH, 0.0f), fH - 1.0f);
        float x0 = floorf(sx), y0 = floorf(sy);
        float x1 = fminf(x0 + 1.0f, fW - 1.0f);
        float y1 = fminf(y0 + 1.0f, fH - 1.0f);
        float wx = sx - x0, wy = sy - y0;

        float m00 = 1e30f, m01 = 1e30f, m10 = 1e30f, m11 = 1e30f;
#pragma unroll 4
        for (int m = c * 64; m < c * 64 + 64; ++m) {
            float px = spx[m], py = spy[m];      // wave-uniform -> broadcast
            float dx0 = x0 - px, dx1 = x1 - px;
            float dy0 = y0 - py, dy1 = y1 - py;
            float sx0 = dx0 * dx0, sx1 = dx1 * dx1;
            float sy0 = dy0 * dy0, sy1 = dy1 * dy1;
            // d is an exact small integer -> d*d exact -> square-compare ==
            // |d|<=45 compare, one op cheaper (no fabs).
            float cx0 = (sx0 <= RAD2) ? sx0 : 1e30f;
            float cx1 = (sx1 <= RAD2) ? sx1 : 1e30f;
            float cy0 = (sy0 <= RAD2) ? sy0 : 1e30f;
            float cy1 = (sy1 <= RAD2) ? sy1 : 1e30f;
            m00 = fminf(m00, cx0 + cy0);
            m01 = fminf(m01, cx1 + cy0);
            m10 = fminf(m10, cx0 + cy1);
            m11 = fminf(m11, cx1 + cy1);
        }
        pm[0][c * 64 + qi] = m00;
        pm[1][c * 64 + qi] = m01;
        pm[2][c * 64 + qi] = m10;
        pm[3][c * 64 + qi] = m11;
        __syncthreads();

        if (t < 64) {                    // chunk-0 wave: qi == t, wx/wy valid
            float a00 = 1e30f, a01 = 1e30f, a10 = 1e30f, a11 = 1e30f;
#pragma unroll
            for (int cc = 0; cc < 8; ++cc) {
                a00 = fminf(a00, pm[0][cc * 64 + t]);
                a01 = fminf(a01, pm[1][cc * 64 + t]);
                a10 = fminf(a10, pm[2][cc * 64 + t]);
                a11 = fminf(a11, pm[3][cc * 64 + t]);
            }
            float v00 = (a00 < 1e29f) ? expf(-a00 * INV2S2) : 0.0f;
            float v01 = (a01 < 1e29f) ? expf(-a01 * INV2S2) : 0.0f;
            float v10 = (a10 < 1e29f) ? expf(-a10 * INV2S2) : 0.0f;
            float v11 = (a11 < 1e29f) ? expf(-a11 * INV2S2) : 0.0f;
            float p = v00 * (1.0f - wx) * (1.0f - wy) + v01 * wx * (1.0f - wy)
                    + v10 * (1.0f - wx) * wy          + v11 * wx * wy;
            float om  = 1.0f - p;
            float raw = -(om * om) * logf(fmaxf(p, 1e-6f));
#pragma unroll
            for (int off = 32; off > 0; off >>= 1) raw += __shfl_down(raw, off);
            if (t == 0) part[64 + b * 8 + g] = raw;
        }
    } else {
        // ---------------- CE loss ----------------
        // Per-batch membership bitmask in LDS (no global flags pass).
        // 16 blocks x 512 threads; block j handles 2048 queries of batch j>>1.
        __shared__ unsigned int mask[QQ / 32];   // 4096 bits = 128 words
        __shared__ float sbuf[8];
        const int j = bi - PT_BLOCKS;
        const int b = j >> 1, half = j & 1;

        if (t < QQ / 32) mask[t] = 0u;
        __syncthreads();
        {
            int q = src_idx[b * PP + t];         // 512 threads <-> P=512
            atomicOr(&mask[q >> 5], 1u << (q & 31)); // idempotent: dup idx ok
        }
        __syncthreads();

        float num = 0.0f, den = 0.0f;
#pragma unroll
        for (int i = 0; i < 4; ++i) {
            int q = half * 2048 + i * 512 + t;
            float2 l = logits[b * QQ + q];
            int tc = (mask[q >> 5] >> (q & 31)) & 1;
            float mx  = fmaxf(l.x, l.y);
            float lse = mx + log1pf(expf(-fabsf(l.x - l.y)));
            float nll = lse - (tc ? l.y : l.x);
            float w   = tc ? 1.0f : 0.5f;
            num += w * nll;
            den += w;
        }
        num = block_reduce(num, sbuf);
        den = block_reduce(den, sbuf);
        if (t == 0) {
            part[2 * j]     = num;
            part[2 * j + 1] = den;
        }
    }

    // ---------------- last-block finalization ----------------
    if (t == 0) {
        __threadfence();                         // release partials (L2 wb)
        unsigned long long old = atomicAdd(&g_done, 1ull);
        s_last = ((old % (unsigned long long)NBLK) ==
                  (unsigned long long)(NBLK - 1)) ? 1u : 0u;
    }
    __syncthreads();
    if (s_last) {
        __threadfence();                         // acquire partials (L2 inv)
        if (t < 64) {
            float num = (t < 16) ? part[2 * t]     : 0.0f;
            float den = (t < 16) ? part[2 * t + 1] : 0.0f;
            float pts = part[64 + t];
#pragma unroll
            for (int off = 32; off > 0; off >>= 1) {
                num += __shfl_down(num, off);
                den += __shfl_down(den, off);
                pts += __shfl_down(pts, off);
            }
            // total = ce_num/ce_den + 5.0 * (0.1 * focal_sum / N)
            if (t == 0) out[0] = num / den + 0.5f * pts / (float)NPTS;
        }
    }
}

// ---------------------------------------------------------------------------
extern "C" void kernel_launch(void* const* d_in, const int* in_sizes, int n_in,
                              void* d_out, int out_size, void* d_ws, size_t ws_size,
                              hipStream_t stream) {
    const float*  tpts    = (const float*)d_in[0];   // target_points (B*P, 2)
    const float*  spts    = (const float*)d_in[1];   // src_points    (B*P, 2)
    const float2* logits  = (const float2*)d_in[2];  // pred_logits   (B, Q, 2)
    // d_in[3] = batch_indices: repeat(arange(B), P) -> implicit in indexing
    const int*    src_idx = (const int*)d_in[4];     // (B, P)
    const int*    ihp     = (const int*)d_in[5];     // img_h scalar
    const int*    iwp     = (const int*)d_in[6];     // img_w scalar

    float* part = (float*)d_ws;
    float* out  = (float*)d_out;

    k_fused<<<NBLK, 512, 0, stream>>>(tpts, spts, logits, src_idx,
                                      ihp, iwp, part, out);
}

// Round 3
// 71.409 us; speedup vs baseline: 1.0380x; 1.0380x over previous
//
#include <hip/hip_runtime.h>
#include <math.h>

// Problem constants (from setup_inputs: B=8, P=512, Q=4096, H=W=512)
#define BB   8
#define PP   512
#define QQ   4096
#define NPTS (BB * PP)
#define RAD2 2025.0f            // 45^2 ; |d|<=45 <=> d*d<=2025 (d is exact int)
#define INV2S2 (1.0f / 450.0f)  // 1/(2*15^2)

#define PT_BLOCKS (BB * 8)      // 64 point blocks: (b, g) = (bi>>3, bi&7)
#define CE_BLOCKS (BB * 2)      // 16 ce blocks:    (b, half) = (j>>1, j&1)
#define NBLK (PT_BLOCKS + CE_BLOCKS)   // 80

// ws layout (floats): [0..31]  CE partials (16 blocks x {num, den})
//                     [64..127] point-loss partials (64 blocks)
// Every slot the finisher reads is written unconditionally each call
// -> poison-safe, no init kernel.

// Completion counter in MODULE memory (never poisoned by the harness).
// Monotonic: each launch adds exactly NBLK; the block whose atomicAdd returns
// old % NBLK == NBLK-1 is the 80th completer of THIS launch -> finalizes.
// No spinning => no deadlock, no dispatch-order assumption. 64-bit => no
// wraparound phase shift.
__device__ unsigned long long g_done = 0ull;

#define ST_AGENT(p, v) __hip_atomic_store((p), (v), __ATOMIC_RELAXED, \
                                          __HIP_MEMORY_SCOPE_AGENT)
#define LD_AGENT(p)    __hip_atomic_load((p), __ATOMIC_RELAXED, \
                                         __HIP_MEMORY_SCOPE_AGENT)

// block-wide sum reduction (blockDim.x multiple of 64, <=512); valid at tid 0.
__device__ inline float block_reduce(float v, float* sbuf) {
#pragma unroll
    for (int off = 32; off > 0; off >>= 1) v += __shfl_down(v, off);
    const int lane = threadIdx.x & 63;
    const int wid  = threadIdx.x >> 6;
    __syncthreads();
    if (lane == 0) sbuf[wid] = v;
    __syncthreads();
    float r = (threadIdx.x < (blockDim.x >> 6)) ? sbuf[threadIdx.x] : 0.0f;
    if (wid == 0) {
#pragma unroll
        for (int off = 32; off > 0; off >>= 1) r += __shfl_down(r, off);
    }
    return r;
}

// ---------------------------------------------------------------------------
// Single fused kernel: blocks [0,64) point loss, blocks [64,80) CE, and the
// last-finishing block does the final scalar reduction. FENCE-FREE protocol:
// partials are agent-scope (sc1) stores that write through the non-coherent
// per-XCD L2; an explicit s_waitcnt vmcnt(0) orders them before the counter
// increment. NO __threadfence() -> no buffer_wbl2 L2 writeback (that flush,
// right after the harness's 256 MiB dirty poison fill, was R2's regression).
__global__ __launch_bounds__(512) void k_fused(
        const float* __restrict__ tpts, const float* __restrict__ spts,
        const float2* __restrict__ logits, const int* __restrict__ src_idx,
        const int* __restrict__ ihp, const int* __restrict__ iwp,
        float* __restrict__ part, float* __restrict__ out) {
    __shared__ unsigned int s_last;
    const int bi = blockIdx.x;
    const int t = threadIdx.x;

    if (bi < PT_BLOCKS) {
        // ---------------- point loss ----------------
        // Wave c handles point-chunk c (64 points, wave-uniform m -> LDS
        // broadcast) for 64 queries (qi = lane). Partial mins combined via
        // LDS; chunk-0 wave finishes (its wx/wy are right for query qi = t).
        __shared__ float spx[PP], spy[PP];
        __shared__ float pm[4][PP];              // [corner][c*64 + qi]
        const int b = bi >> 3, g = bi & 7;
        const float fH = (float)ihp[0];
        const float fW = (float)iwp[0];

        // stage rounded/clipped target pixel coords (512 threads <-> 512 pts)
        {
            float2 tp = ((const float2*)tpts)[b * PP + t];   // vectorized 8B
            float fx = rintf(tp.x / fH * fW);    // round-half-even = jnp.round
            float fy = rintf(tp.y / fW * fH);
            spx[t] = fminf(fmaxf(fx, 0.0f), fW - 1.0f);
            spy[t] = fminf(fmaxf(fy, 0.0f), fH - 1.0f);
        }
        __syncthreads();

        const int qi = t & 63, c = t >> 6;
        const int n = b * PP + g * 64 + qi;
        float2 sp = ((const float2*)spts)[n];                // vectorized 8B
        float sx = fminf(fmaxf(sp.x * fW, 0.0f), fW - 1.0f);
        float sy = fminf(fmaxf(sp.y * fH, 0.0f), fH - 1.0f);
        float x0 = floorf(sx), y0 = floorf(sy);
        float x1 = fminf(x0 + 1.0f, fW - 1.0f);
        float y1 = fminf(y0 + 1.0f, fH - 1.0f);
        float wx = sx - x0, wy = sy - y0;

        float m00 = 1e30f, m01 = 1e30f, m10 = 1e30f, m11 = 1e30f;
#pragma unroll 4
        for (int m = c * 64; m < c * 64 + 64; ++m) {
            float px = spx[m], py = spy[m];      // wave-uniform -> broadcast
            float dx0 = x0 - px, dx1 = x1 - px;
            float dy0 = y0 - py, dy1 = y1 - py;
            float sx0 = dx0 * dx0, sx1 = dx1 * dx1;
            float sy0 = dy0 * dy0, sy1 = dy1 * dy1;
            // d is an exact small integer -> d*d exact -> square-compare ==
            // |d|<=45 compare, one op cheaper (no fabs).
            float cx0 = (sx0 <= RAD2) ? sx0 : 1e30f;
            float cx1 = (sx1 <= RAD2) ? sx1 : 1e30f;
            float cy0 = (sy0 <= RAD2) ? sy0 : 1e30f;
            float cy1 = (sy1 <= RAD2) ? sy1 : 1e30f;
            m00 = fminf(m00, cx0 + cy0);
            m01 = fminf(m01, cx1 + cy0);
            m10 = fminf(m10, cx0 + cy1);
            m11 = fminf(m11, cx1 + cy1);
        }
        pm[0][c * 64 + qi] = m00;
        pm[1][c * 64 + qi] = m01;
        pm[2][c * 64 + qi] = m10;
        pm[3][c * 64 + qi] = m11;
        __syncthreads();

        if (t < 64) {                    // chunk-0 wave: qi == t, wx/wy valid
            float a00 = 1e30f, a01 = 1e30f, a10 = 1e30f, a11 = 1e30f;
#pragma unroll
            for (int cc = 0; cc < 8; ++cc) {
                a00 = fminf(a00, pm[0][cc * 64 + t]);
                a01 = fminf(a01, pm[1][cc * 64 + t]);
                a10 = fminf(a10, pm[2][cc * 64 + t]);
                a11 = fminf(a11, pm[3][cc * 64 + t]);
            }
            float v00 = (a00 < 1e29f) ? expf(-a00 * INV2S2) : 0.0f;
            float v01 = (a01 < 1e29f) ? expf(-a01 * INV2S2) : 0.0f;
            float v10 = (a10 < 1e29f) ? expf(-a10 * INV2S2) : 0.0f;
            float v11 = (a11 < 1e29f) ? expf(-a11 * INV2S2) : 0.0f;
            float p = v00 * (1.0f - wx) * (1.0f - wy) + v01 * wx * (1.0f - wy)
                    + v10 * (1.0f - wx) * wy          + v11 * wx * wy;
            float om  = 1.0f - p;
            float raw = -(om * om) * logf(fmaxf(p, 1e-6f));
#pragma unroll
            for (int off = 32; off > 0; off >>= 1) raw += __shfl_down(raw, off);
            if (t == 0) ST_AGENT(&part[64 + b * 8 + g], raw);
        }
    } else {
        // ---------------- CE loss ----------------
        // Per-batch membership bitmask in LDS (no global flags pass).
        // 16 blocks x 512 threads; block j handles 2048 queries of batch j>>1.
        __shared__ unsigned int mask[QQ / 32];   // 4096 bits = 128 words
        __shared__ float sbuf[8];
        const int j = bi - PT_BLOCKS;
        const int b = j >> 1, half = j & 1;

        if (t < QQ / 32) mask[t] = 0u;
        __syncthreads();
        {
            int q = src_idx[b * PP + t];         // 512 threads <-> P=512
            atomicOr(&mask[q >> 5], 1u << (q & 31)); // idempotent: dup idx ok
        }
        __syncthreads();

        float num = 0.0f, den = 0.0f;
#pragma unroll
        for (int i = 0; i < 4; ++i) {
            int q = half * 2048 + i * 512 + t;
            float2 l = logits[b * QQ + q];
            int tc = (mask[q >> 5] >> (q & 31)) & 1;
            float mx  = fmaxf(l.x, l.y);
            float lse = mx + log1pf(expf(-fabsf(l.x - l.y)));
            float nll = lse - (tc ? l.y : l.x);
            float w   = tc ? 1.0f : 0.5f;
            num += w * nll;
            den += w;
        }
        num = block_reduce(num, sbuf);
        den = block_reduce(den, sbuf);
        if (t == 0) {
            ST_AGENT(&part[2 * j],     num);
            ST_AGENT(&part[2 * j + 1], den);
        }
    }

    // ---------------- last-block finalization (fence-free) ----------------
    if (t == 0) {
        // Order: agent-coherent partial stores must be COMPLETE (at the
        // coherence point) before this block's counter tick is visible.
        // vmcnt(0) waits for store completion; no cache flush involved.
        asm volatile("s_waitcnt vmcnt(0)" ::: "memory");
        unsigned long long old = __hip_atomic_fetch_add(
            &g_done, 1ull, __ATOMIC_RELAXED, __HIP_MEMORY_SCOPE_AGENT);
        s_last = ((old % (unsigned long long)NBLK) ==
                  (unsigned long long)(NBLK - 1)) ? 1u : 0u;
    }
    __syncthreads();
    if (s_last) {
        if (t < 64) {
            // Agent-scope loads bypass the (stale) local L2 -> read the
            // coherence point, which holds every completed partial.
            float num = (t < 16) ? LD_AGENT(&part[2 * t])     : 0.0f;
            float den = (t < 16) ? LD_AGENT(&part[2 * t + 1]) : 0.0f;
            float pts = LD_AGENT(&part[64 + t]);
#pragma unroll
            for (int off = 32; off > 0; off >>= 1) {
                num += __shfl_down(num, off);
                den += __shfl_down(den, off);
                pts += __shfl_down(pts, off);
            }
            // total = ce_num/ce_den + 5.0 * (0.1 * focal_sum / N)
            if (t == 0) out[0] = num / den + 0.5f * pts / (float)NPTS;
        }
    }
}

// ---------------------------------------------------------------------------
extern "C" void kernel_launch(void* const* d_in, const int* in_sizes, int n_in,
                              void* d_out, int out_size, void* d_ws, size_t ws_size,
                              hipStream_t stream) {
    const float*  tpts    = (const float*)d_in[0];   // target_points (B*P, 2)
    const float*  spts    = (const float*)d_in[1];   // src_points    (B*P, 2)
    const float2* logits  = (const float2*)d_in[2];  // pred_logits   (B, Q, 2)
    // d_in[3] = batch_indices: repeat(arange(B), P) -> implicit in indexing
    const int*    src_idx = (const int*)d_in[4];     // (B, P)
    const int*    ihp     = (const int*)d_in[5];     // img_h scalar
    const int*    iwp     = (const int*)d_in[6];     // img_w scalar

    float* part = (float*)d_ws;
    float* out  = (float*)d_out;

    k_fused<<<NBLK, 512, 0, stream>>>(tpts, spts, logits, src_idx,
                                      ihp, iwp, part, out);
}